// Round 1
// baseline (4118.065 us; speedup 1.0000x reference)
//
#include <hip/hip_runtime.h>

#define F_IN 128
#define H1   16
#define C2   8

// ---------------- degree ----------------
__global__ void deg_kernel(const int* __restrict__ col, int E, float* __restrict__ deg) {
    int i = blockIdx.x * blockDim.x + threadIdx.x;
    int stride = gridDim.x * blockDim.x;
    for (int e = i; e < E; e += stride) {
        atomicAdd(&deg[col[e]], 1.0f);
    }
}

// dinv = rsqrt(deg + 1)   (+1 accounts for the self-loop)
__global__ void dinv_kernel(float* __restrict__ deg, int N) {
    int v = blockIdx.x * blockDim.x + threadIdx.x;
    if (v < N) deg[v] = rsqrtf(deg[v] + 1.0f);
}

// ---------------- h1 = x @ W1 ----------------
__global__ void gemm1_kernel(const float* __restrict__ x, const float* __restrict__ W1,
                             float* __restrict__ h1, int N) {
    __shared__ float sW[F_IN * H1];
    for (int i = threadIdx.x; i < F_IN * H1; i += blockDim.x) sW[i] = W1[i];
    __syncthreads();
    int v = blockIdx.x * blockDim.x + threadIdx.x;
    if (v >= N) return;
    float acc[H1];
#pragma unroll
    for (int j = 0; j < H1; ++j) acc[j] = 0.0f;
    const float4* xr = reinterpret_cast<const float4*>(x + (size_t)v * F_IN);
#pragma unroll 8
    for (int k4 = 0; k4 < F_IN / 4; ++k4) {
        float4 xv = xr[k4];
        const float* w = &sW[k4 * 4 * H1];
#pragma unroll
        for (int j = 0; j < H1; ++j) acc[j] += xv.x * w[j];
#pragma unroll
        for (int j = 0; j < H1; ++j) acc[j] += xv.y * w[H1 + j];
#pragma unroll
        for (int j = 0; j < H1; ++j) acc[j] += xv.z * w[2 * H1 + j];
#pragma unroll
        for (int j = 0; j < H1; ++j) acc[j] += xv.w * w[3 * H1 + j];
    }
    float4* ho = reinterpret_cast<float4*>(h1 + (size_t)v * H1);
#pragma unroll
    for (int q = 0; q < H1 / 4; ++q) {
        ho[q] = make_float4(acc[q * 4 + 0], acc[q * 4 + 1], acc[q * 4 + 2], acc[q * 4 + 3]);
    }
}

// ---------------- layer-1 scatter: agg1[c] += h1[r] * dinv[r]*dinv[c] ----------------
__global__ void scatter1_kernel(const int* __restrict__ ei, int E,
                                const float* __restrict__ dinv,
                                const float* __restrict__ h1,
                                float* __restrict__ agg1) {
    int i = blockIdx.x * blockDim.x + threadIdx.x;
    int stride = gridDim.x * blockDim.x;
    for (int e = i; e < E; e += stride) {
        int r = ei[e];
        int c = ei[E + e];
        float norm = dinv[r] * dinv[c];
        const float4* hr = reinterpret_cast<const float4*>(h1 + (size_t)r * H1);
        float* outp = agg1 + (size_t)c * H1;
#pragma unroll
        for (int q = 0; q < H1 / 4; ++q) {
            float4 hv = hr[q];
            atomicAdd(outp + q * 4 + 0, hv.x * norm);
            atomicAdd(outp + q * 4 + 1, hv.y * norm);
            atomicAdd(outp + q * 4 + 2, hv.z * norm);
            atomicAdd(outp + q * 4 + 3, hv.w * norm);
        }
    }
}

// ---------------- finalize layer 1 (+bias, +self-loop, relu) and h2 = h @ W2 ----------------
__global__ void fin1_gemm2_kernel(const float* __restrict__ agg1, const float* __restrict__ h1,
                                  const float* __restrict__ dinv, const float* __restrict__ b1,
                                  const float* __restrict__ W2, float* __restrict__ h2, int N) {
    __shared__ float sW[H1 * C2];
    __shared__ float sb[H1];
    for (int i = threadIdx.x; i < H1 * C2; i += blockDim.x) sW[i] = W2[i];
    for (int i = threadIdx.x; i < H1; i += blockDim.x) sb[i] = b1[i];
    __syncthreads();
    int v = blockIdx.x * blockDim.x + threadIdx.x;
    if (v >= N) return;
    float di = dinv[v];
    float sl = di * di;
    const float4* ar = reinterpret_cast<const float4*>(agg1 + (size_t)v * H1);
    const float4* hr = reinterpret_cast<const float4*>(h1 + (size_t)v * H1);
    float hrelu[H1];
#pragma unroll
    for (int q = 0; q < H1 / 4; ++q) {
        float4 av = ar[q];
        float4 hv = hr[q];
        hrelu[q * 4 + 0] = fmaxf(av.x + hv.x * sl + sb[q * 4 + 0], 0.0f);
        hrelu[q * 4 + 1] = fmaxf(av.y + hv.y * sl + sb[q * 4 + 1], 0.0f);
        hrelu[q * 4 + 2] = fmaxf(av.z + hv.z * sl + sb[q * 4 + 2], 0.0f);
        hrelu[q * 4 + 3] = fmaxf(av.w + hv.w * sl + sb[q * 4 + 3], 0.0f);
    }
    float acc[C2];
#pragma unroll
    for (int j = 0; j < C2; ++j) acc[j] = 0.0f;
#pragma unroll
    for (int k = 0; k < H1; ++k) {
#pragma unroll
        for (int j = 0; j < C2; ++j) acc[j] += hrelu[k] * sW[k * C2 + j];
    }
    float4* ho = reinterpret_cast<float4*>(h2 + (size_t)v * C2);
    ho[0] = make_float4(acc[0], acc[1], acc[2], acc[3]);
    ho[1] = make_float4(acc[4], acc[5], acc[6], acc[7]);
}

// ---------------- layer-2 scatter ----------------
__global__ void scatter2_kernel(const int* __restrict__ ei, int E,
                                const float* __restrict__ dinv,
                                const float* __restrict__ h2,
                                float* __restrict__ agg2) {
    int i = blockIdx.x * blockDim.x + threadIdx.x;
    int stride = gridDim.x * blockDim.x;
    for (int e = i; e < E; e += stride) {
        int r = ei[e];
        int c = ei[E + e];
        float norm = dinv[r] * dinv[c];
        const float4* hr = reinterpret_cast<const float4*>(h2 + (size_t)r * C2);
        float* outp = agg2 + (size_t)c * C2;
#pragma unroll
        for (int q = 0; q < C2 / 4; ++q) {
            float4 hv = hr[q];
            atomicAdd(outp + q * 4 + 0, hv.x * norm);
            atomicAdd(outp + q * 4 + 1, hv.y * norm);
            atomicAdd(outp + q * 4 + 2, hv.z * norm);
            atomicAdd(outp + q * 4 + 3, hv.w * norm);
        }
    }
}

// ---------------- finalize layer 2 + log_softmax ----------------
__global__ void fin2_kernel(const float* __restrict__ agg2, const float* __restrict__ h2,
                            const float* __restrict__ dinv, const float* __restrict__ b2,
                            float* __restrict__ out, int N) {
    __shared__ float sb[C2];
    for (int i = threadIdx.x; i < C2; i += blockDim.x) sb[i] = b2[i];
    __syncthreads();
    int v = blockIdx.x * blockDim.x + threadIdx.x;
    if (v >= N) return;
    float di = dinv[v];
    float sl = di * di;
    const float4* ar = reinterpret_cast<const float4*>(agg2 + (size_t)v * C2);
    const float4* hr = reinterpret_cast<const float4*>(h2 + (size_t)v * C2);
    float z[C2];
#pragma unroll
    for (int q = 0; q < C2 / 4; ++q) {
        float4 av = ar[q];
        float4 hv = hr[q];
        z[q * 4 + 0] = av.x + hv.x * sl + sb[q * 4 + 0];
        z[q * 4 + 1] = av.y + hv.y * sl + sb[q * 4 + 1];
        z[q * 4 + 2] = av.z + hv.z * sl + sb[q * 4 + 2];
        z[q * 4 + 3] = av.w + hv.w * sl + sb[q * 4 + 3];
    }
    float m = z[0];
#pragma unroll
    for (int j = 1; j < C2; ++j) m = fmaxf(m, z[j]);
    float s = 0.0f;
#pragma unroll
    for (int j = 0; j < C2; ++j) s += __expf(z[j] - m);
    float lse = m + logf(s);
    float4* o = reinterpret_cast<float4*>(out + (size_t)v * C2);
    o[0] = make_float4(z[0] - lse, z[1] - lse, z[2] - lse, z[3] - lse);
    o[1] = make_float4(z[4] - lse, z[5] - lse, z[6] - lse, z[7] - lse);
}

extern "C" void kernel_launch(void* const* d_in, const int* in_sizes, int n_in,
                              void* d_out, int out_size, void* d_ws, size_t ws_size,
                              hipStream_t stream) {
    const float* x  = (const float*)d_in[0];
    const int*   ei = (const int*)d_in[1];
    const float* W1 = (const float*)d_in[2];
    const float* b1 = (const float*)d_in[3];
    const float* W2 = (const float*)d_in[4];
    const float* b2 = (const float*)d_in[5];
    float* out = (float*)d_out;

    const int N = in_sizes[0] / F_IN;
    const int E = in_sizes[1] / 2;

    float* ws   = (float*)d_ws;
    float* deg  = ws;                       // N floats (becomes dinv in place)
    float* agg1 = deg + N;                  // 16N
    float* agg2 = agg1 + (size_t)16 * N;    // 8N
    float* h1   = agg2 + (size_t)8 * N;     // 16N
    float* h2   = h1 + (size_t)16 * N;      // 8N

    // zero deg + agg1 + agg2 (25N floats)
    hipMemsetAsync(ws, 0, sizeof(float) * (size_t)25 * N, stream);

    const int TB = 256;
    const int nodeBlocks = (N + TB - 1) / TB;
    const int edgeBlocks = 2048;  // grid-stride

    deg_kernel<<<edgeBlocks, TB, 0, stream>>>(ei + E, E, deg);
    dinv_kernel<<<nodeBlocks, TB, 0, stream>>>(deg, N);
    gemm1_kernel<<<nodeBlocks, TB, 0, stream>>>(x, W1, h1, N);
    scatter1_kernel<<<edgeBlocks, TB, 0, stream>>>(ei, E, deg, h1, agg1);
    fin1_gemm2_kernel<<<nodeBlocks, TB, 0, stream>>>(agg1, h1, deg, b1, W2, h2, N);
    scatter2_kernel<<<edgeBlocks, TB, 0, stream>>>(ei, E, deg, h2, agg2);
    fin2_kernel<<<nodeBlocks, TB, 0, stream>>>(agg2, h2, deg, b2, out, N);
}

// Round 2
// 476.082 us; speedup vs baseline: 8.6499x; 8.6499x over previous
//
#include <hip/hip_runtime.h>

#define F_IN 128
#define H1   16
#define C2   8
#define SCAN_B 256

// ---------------- int histogram of destinations ----------------
__global__ void hist_kernel(const int* __restrict__ col, int E, int* __restrict__ cnt) {
    int i = blockIdx.x * blockDim.x + threadIdx.x;
    int stride = gridDim.x * blockDim.x;
    for (int e = i; e < E; e += stride) {
        atomicAdd(&cnt[col[e]], 1);
    }
}

// dinv = rsqrt(cnt + 1)   (+1 accounts for the self-loop)
__global__ void dinv_kernel(const int* __restrict__ cnt, float* __restrict__ dinv, int N) {
    int v = blockIdx.x * blockDim.x + threadIdx.x;
    if (v < N) dinv[v] = rsqrtf((float)cnt[v] + 1.0f);
}

// ---------------- exclusive scan (3 kernels) ----------------
__global__ void scanA_kernel(const int* __restrict__ cnt, int N,
                             int* __restrict__ ptr, int* __restrict__ bsum) {
    __shared__ int s[SCAN_B];
    int i = blockIdx.x * SCAN_B + threadIdx.x;
    int v = (i < N) ? cnt[i] : 0;
    s[threadIdx.x] = v;
    __syncthreads();
    int incl = v;
    for (int off = 1; off < SCAN_B; off <<= 1) {
        int t = (threadIdx.x >= off) ? s[threadIdx.x - off] : 0;
        __syncthreads();
        incl += t;
        s[threadIdx.x] = incl;
        __syncthreads();
    }
    if (i < N) ptr[i] = incl - v;
    if (threadIdx.x == SCAN_B - 1) bsum[blockIdx.x] = incl;
}

__global__ void scanB_kernel(int* __restrict__ bsum, int* __restrict__ boff, int NB) {
    __shared__ int s[1024];
    int v = (threadIdx.x < NB) ? bsum[threadIdx.x] : 0;
    s[threadIdx.x] = v;
    __syncthreads();
    int incl = v;
    for (int off = 1; off < 1024; off <<= 1) {
        int t = (threadIdx.x >= off) ? s[threadIdx.x - off] : 0;
        __syncthreads();
        incl += t;
        s[threadIdx.x] = incl;
        __syncthreads();
    }
    boff[threadIdx.x] = incl - v;
}

__global__ void scanC_kernel(int* __restrict__ ptr, const int* __restrict__ boff, int N) {
    int i = blockIdx.x * SCAN_B + threadIdx.x;
    if (i < N) ptr[i] += boff[blockIdx.x];
}

// ---------------- CSR build: csr[pos] = src, grouped by destination ----------------
__global__ void grab_kernel(const int* __restrict__ ei, int E,
                            const int* __restrict__ ptr, int* __restrict__ cur,
                            int* __restrict__ csr) {
    int i = blockIdx.x * blockDim.x + threadIdx.x;
    int stride = gridDim.x * blockDim.x;
    for (int e = i; e < E; e += stride) {
        int r = ei[e];
        int c = ei[E + e];
        int pos = ptr[c] + atomicAdd(&cur[c], 1);
        csr[pos] = r;
    }
}

// ---------------- h1s = (x @ W1) * dinv[v] ----------------
__global__ void gemm1_kernel(const float* __restrict__ x, const float* __restrict__ W1,
                             const float* __restrict__ dinv, float* __restrict__ h1s, int N) {
    __shared__ float sW[F_IN * H1];
    for (int i = threadIdx.x; i < F_IN * H1; i += blockDim.x) sW[i] = W1[i];
    __syncthreads();
    int v = blockIdx.x * blockDim.x + threadIdx.x;
    if (v >= N) return;
    float acc[H1];
#pragma unroll
    for (int j = 0; j < H1; ++j) acc[j] = 0.0f;
    const float4* xr = reinterpret_cast<const float4*>(x + (size_t)v * F_IN);
#pragma unroll 8
    for (int k4 = 0; k4 < F_IN / 4; ++k4) {
        float4 xv = xr[k4];
        const float* w = &sW[k4 * 4 * H1];
#pragma unroll
        for (int j = 0; j < H1; ++j) acc[j] += xv.x * w[j];
#pragma unroll
        for (int j = 0; j < H1; ++j) acc[j] += xv.y * w[H1 + j];
#pragma unroll
        for (int j = 0; j < H1; ++j) acc[j] += xv.z * w[2 * H1 + j];
#pragma unroll
        for (int j = 0; j < H1; ++j) acc[j] += xv.w * w[3 * H1 + j];
    }
    float di = dinv[v];
    float4* ho = reinterpret_cast<float4*>(h1s + (size_t)v * H1);
#pragma unroll
    for (int q = 0; q < H1 / 4; ++q) {
        ho[q] = make_float4(acc[q * 4 + 0] * di, acc[q * 4 + 1] * di,
                            acc[q * 4 + 2] * di, acc[q * 4 + 3] * di);
    }
}

// ---------------- gather layer 1 + relu + GEMM2 fused ----------------
// 256 threads = 16 nodes x 16 feature-lanes
__global__ void gather1_kernel(const int* __restrict__ ptr, const int* __restrict__ cnt,
                               const int* __restrict__ csr, const float* __restrict__ h1s,
                               const float* __restrict__ dinv, const float* __restrict__ b1,
                               const float* __restrict__ W2, float* __restrict__ h2s, int N) {
    __shared__ float sh[16][H1 + 1];
    __shared__ float sW[H1 * C2];
    __shared__ float sb[H1];
    for (int i = threadIdx.x; i < H1 * C2; i += blockDim.x) sW[i] = W2[i];
    for (int i = threadIdx.x; i < H1; i += blockDim.x) sb[i] = b1[i];
    __syncthreads();

    int nl = threadIdx.x >> 4;       // 0..15
    int f  = threadIdx.x & 15;       // 0..15
    int v  = blockIdx.x * 16 + nl;
    if (v < N) {
        int start = ptr[v];
        int end   = start + cnt[v];
        float acc = h1s[(size_t)v * H1 + f];   // self-loop term
        for (int e = start; e < end; ++e) {
            int src = csr[e];
            acc += h1s[(size_t)src * H1 + f];
        }
        sh[nl][f] = fmaxf(dinv[v] * acc + sb[f], 0.0f);
    }
    __syncthreads();

    if (threadIdx.x < 16 * C2) {
        int nl2 = threadIdx.x >> 3;  // 0..15
        int j   = threadIdx.x & 7;   // 0..7
        int v2  = blockIdx.x * 16 + nl2;
        if (v2 < N) {
            float dot = 0.0f;
#pragma unroll
            for (int k = 0; k < H1; ++k) dot += sh[nl2][k] * sW[k * C2 + j];
            h2s[(size_t)v2 * C2 + j] = dot * dinv[v2];
        }
    }
}

// ---------------- gather layer 2 + bias + log_softmax fused ----------------
// 256 threads = 32 nodes x 8 class-lanes
__global__ void gather2_kernel(const int* __restrict__ ptr, const int* __restrict__ cnt,
                               const int* __restrict__ csr, const float* __restrict__ h2s,
                               const float* __restrict__ dinv, const float* __restrict__ b2,
                               float* __restrict__ out, int N) {
    __shared__ float sb[C2];
    if (threadIdx.x < C2) sb[threadIdx.x] = b2[threadIdx.x];
    __syncthreads();

    int nl = threadIdx.x >> 3;       // 0..31
    int j  = threadIdx.x & 7;        // 0..7
    int v  = blockIdx.x * 32 + nl;
    if (v >= N) return;

    int start = ptr[v];
    int end   = start + cnt[v];
    float acc = h2s[(size_t)v * C2 + j];      // self-loop term
    for (int e = start; e < end; ++e) {
        int src = csr[e];
        acc += h2s[(size_t)src * C2 + j];
    }
    float z = dinv[v] * acc + sb[j];

    // log-softmax across the 8 lanes of this node
    float m = z;
#pragma unroll
    for (int mask = 1; mask < 8; mask <<= 1)
        m = fmaxf(m, __shfl_xor(m, mask, 8));
    float ex = __expf(z - m);
    float s = ex;
#pragma unroll
    for (int mask = 1; mask < 8; mask <<= 1)
        s += __shfl_xor(s, mask, 8);
    float lse = m + logf(s);
    out[(size_t)v * C2 + j] = z - lse;
}

extern "C" void kernel_launch(void* const* d_in, const int* in_sizes, int n_in,
                              void* d_out, int out_size, void* d_ws, size_t ws_size,
                              hipStream_t stream) {
    const float* x  = (const float*)d_in[0];
    const int*   ei = (const int*)d_in[1];
    const float* W1 = (const float*)d_in[2];
    const float* b1 = (const float*)d_in[3];
    const float* W2 = (const float*)d_in[4];
    const float* b2 = (const float*)d_in[5];
    float* out = (float*)d_out;

    const int N = in_sizes[0] / F_IN;
    const int E = in_sizes[1] / 2;

    // workspace layout
    int*   cnt  = (int*)d_ws;                 // N
    int*   cur  = cnt + N;                    // N
    int*   ptr  = cur + N;                    // N
    int*   bsum = ptr + N;                    // 1024
    int*   boff = bsum + 1024;                // 1024
    float* dinv = (float*)(boff + 1024);      // N
    float* h1s  = dinv + N;                   // 16N
    float* h2s  = h1s + (size_t)16 * N;       // 8N
    int*   csr  = (int*)(h2s + (size_t)8 * N);// E

    // zero cnt + cur (adjacent)
    hipMemsetAsync(cnt, 0, sizeof(int) * (size_t)2 * N, stream);

    const int TB = 256;
    const int nodeBlocks = (N + TB - 1) / TB;
    const int edgeBlocks = 2048;
    const int NB1 = (N + SCAN_B - 1) / SCAN_B;   // 391 for N=100000 (must be <= 1024)

    hist_kernel<<<edgeBlocks, TB, 0, stream>>>(ei + E, E, cnt);
    dinv_kernel<<<nodeBlocks, TB, 0, stream>>>(cnt, dinv, N);
    scanA_kernel<<<NB1, SCAN_B, 0, stream>>>(cnt, N, ptr, bsum);
    scanB_kernel<<<1, 1024, 0, stream>>>(bsum, boff, NB1);
    scanC_kernel<<<NB1, SCAN_B, 0, stream>>>(ptr, boff, N);
    grab_kernel<<<edgeBlocks, TB, 0, stream>>>(ei, E, ptr, cur, csr);
    gemm1_kernel<<<nodeBlocks, TB, 0, stream>>>(x, W1, dinv, h1s, N);
    gather1_kernel<<<(N + 15) / 16, TB, 0, stream>>>(ptr, cnt, csr, h1s, dinv, b1, W2, h2s, N);
    gather2_kernel<<<(N + 31) / 32, TB, 0, stream>>>(ptr, cnt, csr, h2s, dinv, b2, out, N);
}